// Round 6
// baseline (443.589 us; speedup 1.0000x reference)
//
#include <hip/hip_runtime.h>

// LengthRegulator: B=64, T=512, D=384, MAX_LEN=4096
// R7: ZERO-BARRIER wave-autonomous rewrite of R5 (the 419.5 us best).
//   Evidence: R5 (-12 us removing prologue) and R6 (+16 us shrinking per-wave MLP)
//   => block-level serialization around __syncthreads + prologue/drain is the
//   remaining structural overhead; harness fill proves 6.3 TB/s writes need no
//   occupancy, just an ungated store stream.
//   Each WAVE: redundant full scan of duration[b,:] (8 tokens/lane, int4 loads,
//   local scan + 6 shfl_up steps), scatters its private 16-row idx window into
//   its own LDS slice (intra-wave order only), then copies 16 rows with the
//   proven 12-deep float4 pipeline. No __syncthreads anywhere.
// Swizzle: b = blockIdx%64 -> XCD = blockIdx%8 == b%8 (x slice L2-pinned).
// Output layout (flat float32): [B*ML*D] out, then [B] mel_len (as float).

#define T_DIM 512
#define D_DIM 384
#define D4    (D_DIM / 4)      // 96 float4 per row
#define WR    16               // output rows per wave
#define BLOCK 512
#define NWAVE (BLOCK / 64)     // 8
#define ROWS_BLK (WR * NWAVE)  // 128 rows per block
#define ITER  ((WR * D4) / 64) // 24 float4 per lane

typedef float vfloat4 __attribute__((ext_vector_type(4)));
typedef int   vint4   __attribute__((ext_vector_type(4)));

__global__ __launch_bounds__(BLOCK) void lr_fused_kernel(
    const float* __restrict__ x,         // [B, T, D]
    const int*   __restrict__ duration,  // [B, T]
    float*       __restrict__ out,       // [B, ML, D] + [B] mel tail
    int B, int ML)
{
    __shared__ int s_idx[NWAVE][WR];     // per-wave private windows (512 B)

    const int b     = blockIdx.x % B;    // XCD pin: b % 8 == blockIdx % 8
    const int chunk = blockIdx.x / B;    // 0..31
    const int tid   = threadIdx.x;
    const int lane  = tid & 63;
    const int wid   = tid >> 6;
    const int w0    = chunk * ROWS_BLK + wid * WR;  // wave's first output row

    // ---- per-wave redundant scan of duration[b,:]: 8 tokens/lane ----
    const vint4* __restrict__ dur4 = (const vint4*)(duration + b * T_DIM);
    const vint4 da = dur4[2 * lane];
    const vint4 db = dur4[2 * lane + 1];
    int d[8]   = {da.x, da.y, da.z, da.w, db.x, db.y, db.z, db.w};
    int lcs[8];                          // lane-local inclusive csum
    lcs[0] = d[0];
    #pragma unroll
    for (int k = 1; k < 8; ++k) lcs[k] = lcs[k - 1] + d[k];
    int incl = lcs[7];                   // inclusive scan of lane totals
    #pragma unroll
    for (int off = 1; off < 64; off <<= 1) {
        const int u = __shfl_up(incl, off);
        if (lane >= off) incl += u;
    }
    const int E   = incl - lcs[7];       // exclusive base of this lane's tokens
    const int mel = __shfl(incl, 63);    // total = mel_len

    // init wave window to "masked"
    if (lane < WR) s_idx[wid][lane] = -1;

    // ---- scatter: token 8*lane+k owns rows [E+lcs[k]-d[k], E+lcs[k]);
    //      write overlap with this wave's window [w0, w0+WR). ----
    #pragma unroll
    for (int k = 0; k < 8; ++k) {
        const int e = E + lcs[k];
        const int s = e - d[k];
        const int lo = s > w0 ? s : w0;
        const int hi = e < w0 + WR ? e : w0 + WR;
        for (int p = lo; p < hi; ++p) s_idx[wid][p - w0] = 8 * lane + k;
    }
    // Intra-wave ordering only: fence compiler motion + drain this wave's DS ops.
    __builtin_amdgcn_wave_barrier();
    __asm__ volatile("s_waitcnt lgkmcnt(0)" ::: "memory");

    if (blockIdx.x < B && tid == 0)      // chunk==0 block of batch b
        out[(long long)B * ML * D_DIM + b] = (float)mel;

    // ---- gather copy: 16 rows x 96 float4, 12-deep pipeline ----
    const vfloat4* __restrict__ x4   = (const vfloat4*)x;
    vfloat4*       __restrict__ out4 = (vfloat4*)out;
    const long long out_base = ((long long)b * ML + w0) * D4;
    const long long x_base   = (long long)b * T_DIM * D4;

    #pragma unroll 12
    for (int i = 0; i < ITER; ++i) {
        const int flat = lane + i * 64;
        const int r = flat / D4;            // constant divisor -> magic mul
        const int j = flat - r * D4;
        const int t = s_idx[wid][r];        // LDS broadcast, wave-local
        vfloat4 vv = (vfloat4)(0.f, 0.f, 0.f, 0.f);
        if (t >= 0) vv = x4[x_base + (long long)t * D4 + j];
        out4[out_base + flat] = vv;         // plain store (nt A/B'd out previously)
    }
}

extern "C" void kernel_launch(void* const* d_in, const int* in_sizes, int n_in,
                              void* d_out, int out_size, void* d_ws, size_t ws_size,
                              hipStream_t stream) {
    const float* x   = (const float*)d_in[0];
    const int*   dur = (const int*)d_in[1];
    float*       out = (float*)d_out;
    (void)d_ws; (void)ws_size;

    const int B  = in_sizes[1] / T_DIM;                 // 64
    const int ML = (out_size - B) / (B * D_DIM);        // 4096

    const int grid = B * (ML / ROWS_BLK);               // 2048 blocks
    hipLaunchKernelGGL(lr_fused_kernel, dim3(grid), dim3(BLOCK), 0, stream,
                       x, dur, out, B, ML);
}